// Round 7
// baseline (381.163 us; speedup 1.0000x reference)
//
#include <hip/hip_runtime.h>

typedef __attribute__((ext_vector_type(8))) short bf16x8;
typedef __attribute__((ext_vector_type(4))) short bf16x4;
typedef __attribute__((ext_vector_type(4))) float f32x4;

#define BB 1024
#define TT 256
#define DD 63
#define HH 128
#define CHUNK 4    // 4 batch rows/block, grid 256 = 1 block/CU
#define HSTR 136   // shorts per h row (128+8); rows are batch (16, 4 valid)
#define XSTR 72    // shorts per x row (64+8)

// Barrier that drains only LDS (lgkmcnt), NOT outstanding global loads.
#define LDS_BARRIER() asm volatile("s_waitcnt lgkmcnt(0)\n\ts_barrier" ::: "memory")

__device__ __forceinline__ short f2bf(float f) {
  unsigned u = __builtin_bit_cast(unsigned, f);
  u = (u + 0x7FFFu + ((u >> 16) & 1u)) >> 16;   // RNE
  return (short)u;
}
__device__ __forceinline__ float sigm(float x) {
  return __builtin_amdgcn_rcpf(1.f + __expf(-x));   // bounded for any finite/inf x
}
__device__ __forceinline__ float tanh_fast(float x) {
  float e = __expf(2.f * x);
  return 1.f - 2.f * __builtin_amdgcn_rcpf(e + 1.f); // saturates to +-1
}

// R7 structure (transposed GEMM): A = weight tile (m = gate col on l15),
// B = [h;x]^T (n = batch row on l15), D: lane(l15=batch, quad) reg p =
// gates[batch l15][col w*16+quad*4+p]. All 4 gates for one (batch,col) sit in
// matching regs of the 4 accumulators -> elementwise is IN-REGISTER:
//   - no gate-redistribute LDS round trip (R6's gsc write/drain/read gone),
//   - h written back with ONE ds_write_b64 per lane,
//   - one LDS round trip + one lgkm-only barrier per timestep.
// Batch rows 4..15 are padding; sigm/tanh bound any garbage so no masking.
// Kept lessons: launch_bounds min-waves=2 (R4: 4 => VGPR clamp 64 => weight
// spill, 177MB scratch); grid=256 => exactly 1 block/CU (R5: no co-residency).
__global__ __launch_bounds__(512, 2)
void lstm_fwd_kernel(const float* __restrict__ X,
                     const float* __restrict__ Wih,
                     const float* __restrict__ Whh,
                     const float* __restrict__ bih,
                     const float* __restrict__ bhh,
                     const float* __restrict__ Wfc,
                     float* __restrict__ out) {
  __shared__ __align__(16) short hbuf[2 * 16 * HSTR];  // h^T (bf16) double-buffered, row=batch
  __shared__ __align__(16) short xbuf[2 * 16 * XSTR];  // x^T (bf16), 2 slots, row=batch
  __shared__ __align__(16) float fst[4 * HH];          // epilogue h_f staging

  const int tid  = threadIdx.x;
  const int wave = tid >> 6;
  const int lane = tid & 63;
  const int quad = lane >> 4;
  const int l15  = lane & 15;
  const int b0   = blockIdx.x * CHUNK;

  // ---- register-resident W fragments as MFMA *A* operands ----
  // A[m=l15][k=quad*8+j], m -> col (g*128 + wave*16 + l15). Same data as R6.
  bf16x8 Ah[4][4];   // [gate][kstep], W_hh
  bf16x8 Axw[4][2];  // [gate][kstep], W_ih (K padded 63->64)
  f32x4  bias[4];    // bias per acc reg p: col = wave*16 + quad*4 + p
#pragma unroll
  for (int g = 0; g < 4; ++g) {
    const int n = g * 128 + wave * 16 + l15;
    const float* wr = Whh + (size_t)n * HH;
#pragma unroll
    for (int ks = 0; ks < 4; ++ks) {
      const int k0 = ks * 32 + quad * 8;
      f32x4 w0 = *(const f32x4*)(wr + k0);
      f32x4 w1 = *(const f32x4*)(wr + k0 + 4);
      bf16x8 v;
#pragma unroll
      for (int jj = 0; jj < 4; ++jj) { v[jj] = f2bf(w0[jj]); v[4 + jj] = f2bf(w1[jj]); }
      Ah[g][ks] = v;
    }
    const float* xr = Wih + (size_t)n * DD;
#pragma unroll
    for (int ks = 0; ks < 2; ++ks) {
      const int k0 = ks * 32 + quad * 8;
      bf16x8 v;
#pragma unroll
      for (int jj = 0; jj < 8; ++jj) {
        const int k = k0 + jj;
        v[jj] = (k < DD) ? f2bf(xr[k]) : (short)0;
      }
      Axw[g][ks] = v;
    }
    const int cb = g * 128 + wave * 16 + quad * 4;
    f32x4 b1 = *(const f32x4*)&bih[cb];
    f32x4 b2 = *(const f32x4*)&bhh[cb];
    bias[g] = b1 + b2;
  }

  // zero both LDS buffers once (h(0)=0; batch rows 4..15 and x pad stay benign)
  for (int i = tid; i < 2 * 16 * HSTR; i += 512) hbuf[i] = 0;
  for (int i = tid; i < 2 * 16 * XSTR; i += 512) xbuf[i] = 0;

  // x prefetch: 4 rows x 63 cols = 252 threads; distance-2 pipeline
  const int xrow = tid / DD;
  const int xd   = tid - xrow * DD;
  const bool xthr = (tid < CHUNK * DD);
  const float* xptr = X + ((size_t)(b0 + xrow) * TT) * DD + xd;
  float xv_pend = 0.f;
  __syncthreads();                 // zero-fill visible before seeding slot 0
  if (xthr) {
    xbuf[xrow * XSTR + xd] = f2bf(xptr[0]);   // slot 0 = x(0)
    xv_pend = xptr[DD];                        // x(1)
    xptr += 2 * DD;
  }
  __syncthreads();

  f32x4 cc = {0.f, 0.f, 0.f, 0.f};
  f32x4 hvreg = {0.f, 0.f, 0.f, 0.f};

  for (int t = 0; t < TT; ++t) {
    const int xcur = (t & 1) * (16 * XSTR);
    const int hcur = (t & 1) * (16 * HSTR);

    // issue x(t+2) load early; stays in flight across the lgkm-only barrier
    float xv_new = 0.f;
    const bool pf2 = xthr && (t + 2 < TT);
    if (pf2) { xv_new = *xptr; xptr += DD; }

    // B-fragments: B[k=quad*8+j][n=l15] -> row l15 (batch), cols = k
    bf16x8 Bh_[4], Bx_[2];
#pragma unroll
    for (int ks = 0; ks < 4; ++ks)
      Bh_[ks] = *(const bf16x8*)&hbuf[hcur + l15 * HSTR + ks * 32 + quad * 8];
#pragma unroll
    for (int ks = 0; ks < 2; ++ks)
      Bx_[ks] = *(const bf16x8*)&xbuf[xcur + l15 * XSTR + ks * 32 + quad * 8];

    // ---- MFMA: acc[g] = bias[g] + W_g @ [h;x]^T (4 independent chains) ----
    f32x4 acc[4];
#pragma unroll
    for (int g = 0; g < 4; ++g)
      acc[g] = __builtin_amdgcn_mfma_f32_16x16x32_bf16(Ah[g][0], Bh_[0], bias[g], 0, 0, 0);
#pragma unroll
    for (int ks = 1; ks < 4; ++ks)
#pragma unroll
      for (int g = 0; g < 4; ++g)
        acc[g] = __builtin_amdgcn_mfma_f32_16x16x32_bf16(Ah[g][ks], Bh_[ks], acc[g], 0, 0, 0);
#pragma unroll
    for (int ks = 0; ks < 2; ++ks)
#pragma unroll
      for (int g = 0; g < 4; ++g)
        acc[g] = __builtin_amdgcn_mfma_f32_16x16x32_bf16(Axw[g][ks], Bx_[ks], acc[g], 0, 0, 0);

    // ---- elementwise: fully in-register, 4 (batch=l15, col=w*16+q*4+p) each ----
    bf16x4 hp;
#pragma unroll
    for (int p = 0; p < 4; ++p) {
      const float iv = sigm(acc[0][p]);
      const float fv = sigm(acc[1][p]);
      const float gv = tanh_fast(acc[2][p]);
      const float ov = sigm(acc[3][p]);
      cc[p] = fv * cc[p] + iv * gv;
      hvreg[p] = ov * tanh_fast(cc[p]);
      hp[p] = f2bf(hvreg[p]);
    }
    *(bf16x4*)&hbuf[(hcur ^ (16 * HSTR)) + l15 * HSTR + wave * 16 + quad * 4] = hp;

    if (xthr && (t + 1 < TT))
      xbuf[(xcur ^ (16 * XSTR)) + xrow * XSTR + xd] = f2bf(xv_pend);
    xv_pend = xv_new;
    LDS_BARRIER();   // the ONE barrier: h/x produced -> consumed next step
  }

  // ---- epilogue: forward half of FC (fp32, no bias) ----
  if (l15 < 4)
    *(f32x4*)&fst[l15 * HH + wave * 16 + quad * 4] = hvreg;
  __syncthreads();
  if (tid < CHUNK * 14) {
    const int rr = tid / 14, o = tid - rr * 14;
    const float* wr = Wfc + (size_t)o * (2 * HH);
    float acc = 0.f;
#pragma unroll 16
    for (int k = 0; k < HH; ++k) acc += wr[k] * fst[rr * HH + k];
    out[(size_t)(b0 + rr) * 14 + o] = acc;
  }
}

// Backward direction collapses to ONE cell step on x[:,T-1] (h0=c0=0),
// done in exact fp32, plus the backward half of the FC (+ biases).
__global__ __launch_bounds__(256, 2)
void lstm_bwd_fc_kernel(const float* __restrict__ X,
                        const float* __restrict__ Wih_b,
                        const float* __restrict__ bih_b,
                        const float* __restrict__ bhh_b,
                        const float* __restrict__ Wfc,
                        const float* __restrict__ bfc,
                        float* __restrict__ out) {
  __shared__ float xl[DD];
  __shared__ float glb[4 * HH];
  __shared__ float hl[HH];
  __shared__ float pl[14 * 8];
  const int b = blockIdx.x;
  const int tid = threadIdx.x;

  if (tid < DD) xl[tid] = X[((size_t)b * TT + (TT - 1)) * DD + tid];
  __syncthreads();

#pragma unroll
  for (int u = 0; u < 2; ++u) {
    const int n = tid * 2 + u;
    const float* wr = Wih_b + (size_t)n * DD;
    float acc = bih_b[n] + bhh_b[n];
#pragma unroll
    for (int k = 0; k < DD; ++k) acc += wr[k] * xl[k];
    glb[n] = acc;
  }
  __syncthreads();

  if (tid < HH) {
    float iv = sigm(glb[0 * HH + tid]);
    float gv = tanh_fast(glb[2 * HH + tid]);
    float ov = sigm(glb[3 * HH + tid]);
    hl[tid] = ov * tanh_fast(iv * gv);   // c = f*0 + i*g
  }
  __syncthreads();

  if (tid < 14 * 8) {
    const int o = tid >> 3, kp = tid & 7;
    const float* wr = Wfc + (size_t)o * (2 * HH) + HH;
    float acc = 0.f;
#pragma unroll
    for (int i = 0; i < 16; ++i) {
      const int jj = kp * 16 + i;
      acc += wr[jj] * hl[jj];
    }
    pl[tid] = acc;
  }
  __syncthreads();

  if (tid < 14) {
    float acc = bfc[tid];
#pragma unroll
    for (int i = 0; i < 8; ++i) acc += pl[tid * 8 + i];
    out[(size_t)b * 14 + tid] += acc;   // add to forward partial
  }
}

extern "C" void kernel_launch(void* const* d_in, const int* in_sizes, int n_in,
                              void* d_out, int out_size, void* d_ws, size_t ws_size,
                              hipStream_t stream) {
  const float* X     = (const float*)d_in[0];
  const float* Wih_f = (const float*)d_in[1];
  const float* Whh_f = (const float*)d_in[2];
  const float* bih_f = (const float*)d_in[3];
  const float* bhh_f = (const float*)d_in[4];
  const float* Wih_b = (const float*)d_in[5];
  // d_in[6] = W_hh_b: unused (backward dir needs only one step from zero state)
  const float* bih_b = (const float*)d_in[7];
  const float* bhh_b = (const float*)d_in[8];
  const float* Wfc   = (const float*)d_in[9];
  const float* bfc   = (const float*)d_in[10];
  float* out = (float*)d_out;

  lstm_fwd_kernel<<<BB / CHUNK, 512, 0, stream>>>(X, Wih_f, Whh_f, bih_f, bhh_f, Wfc, out);
  lstm_bwd_fc_kernel<<<BB, 256, 0, stream>>>(X, Wih_b, bih_b, bhh_b, Wfc, bfc, out);
}

// Round 8
// 303.084 us; speedup vs baseline: 1.2576x; 1.2576x over previous
//
#include <hip/hip_runtime.h>

typedef __attribute__((ext_vector_type(8))) short bf16x8;
typedef __attribute__((ext_vector_type(4))) float f32x4;

#define BB 1024
#define TT 256
#define DD 63
#define HH 128
#define CHUNK 4    // 4 batch rows/block, grid 256 = 1 block/CU
#define HSTR 160   // shorts; 80 dwords ≡ 16 (mod 32): broadcast b128 reads exactly 2-way (free)
#define XSTR 96    // shorts; 48 dwords ≡ 16 (mod 32)

// Barrier that drains only LDS (lgkmcnt), NOT outstanding global loads.
#define LDS_BARRIER() asm volatile("s_waitcnt lgkmcnt(0)\n\ts_barrier" ::: "memory")

__device__ __forceinline__ short f2bf(float f) {
  unsigned u = __builtin_bit_cast(unsigned, f);
  u = (u + 0x7FFFu + ((u >> 16) & 1u)) >> 16;   // RNE
  return (short)u;
}
__device__ __forceinline__ float sigm(float x) {
  return __builtin_amdgcn_rcpf(1.f + __expf(-x));
}
__device__ __forceinline__ float tanh_fast(float x) {
  float e = __expf(2.f * x);
  return 1.f - 2.f * __builtin_amdgcn_rcpf(e + 1.f);
}

// R8: transposed GEMM (A=weights, B=[h;x]^T) with DUPLICATE-GROUP trick.
// B-frags read with l15&3 broadcast -> D rows 4..15 duplicate batches 0..3.
// Duplicate group p = l15>>2 processes register p only: every lane owns
// exactly ONE valid element (batch=l15&3, col=wave*16+quad*4+p).
//  - elementwise: 1 elem/lane, zero garbage (R7 wasted 4x on 1/8-rate trans)
//  - no gate-redistribution LDS round trip (R6's gsc)
//  - one ds_write_b16/lane for h; ONE lgkm-only barrier per step
//  - HSTR=160/XSTR=96: broadcast reads exactly 2-way (R7's 136 was 4-8 way)
// Kept: launch_bounds min-waves=2 (R4: 4 => VGPR clamp 64 => weight spill);
// grid=256 = 1 block/CU (R5: no 2-block co-residency under this bound).
__global__ __launch_bounds__(512, 2)
void lstm_fwd_kernel(const float* __restrict__ X,
                     const float* __restrict__ Wih,
                     const float* __restrict__ Whh,
                     const float* __restrict__ bih,
                     const float* __restrict__ bhh,
                     const float* __restrict__ Wfc,
                     float* __restrict__ out) {
  __shared__ __align__(16) short hbuf[2 * 4 * HSTR];   // h^T (bf16), rows=batch 0..3, dbuf
  __shared__ __align__(16) short xbuf[2 * 4 * XSTR];   // x^T (bf16), rows=batch 0..3, 2 slots
  __shared__ __align__(16) float fst[4 * HH];          // epilogue h_f staging

  const int tid  = threadIdx.x;
  const int wave = tid >> 6;
  const int lane = tid & 63;
  const int quad = lane >> 4;
  const int l15  = lane & 15;
  const int b0   = blockIdx.x * CHUNK;
  const int br   = l15 & 3;        // this lane's batch row
  const int p    = l15 >> 2;       // duplicate-group index = accumulator reg to keep

  // ---- register-resident W fragments as MFMA A operands ----
  // A[m=l15][k=quad*8+j], m -> gate col (g*128 + wave*16 + l15)
  bf16x8 Ah[4][4];   // [gate][kstep], W_hh
  bf16x8 Axw[4][2];  // [gate][kstep], W_ih (K padded 63->64)
  f32x4  bias[4];    // bias per acc reg q: col = wave*16 + quad*4 + q
#pragma unroll
  for (int g = 0; g < 4; ++g) {
    const int n = g * 128 + wave * 16 + l15;
    const float* wr = Whh + (size_t)n * HH;
#pragma unroll
    for (int ks = 0; ks < 4; ++ks) {
      const int k0 = ks * 32 + quad * 8;
      f32x4 w0 = *(const f32x4*)(wr + k0);
      f32x4 w1 = *(const f32x4*)(wr + k0 + 4);
      bf16x8 v;
#pragma unroll
      for (int jj = 0; jj < 4; ++jj) { v[jj] = f2bf(w0[jj]); v[4 + jj] = f2bf(w1[jj]); }
      Ah[g][ks] = v;
    }
    const float* xr = Wih + (size_t)n * DD;
#pragma unroll
    for (int ks = 0; ks < 2; ++ks) {
      const int k0 = ks * 32 + quad * 8;
      bf16x8 v;
#pragma unroll
      for (int jj = 0; jj < 8; ++jj) {
        const int k = k0 + jj;
        v[jj] = (k < DD) ? f2bf(xr[k]) : (short)0;
      }
      Axw[g][ks] = v;
    }
    const int cb = g * 128 + wave * 16 + quad * 4;
    f32x4 b1 = *(const f32x4*)&bih[cb];
    f32x4 b2 = *(const f32x4*)&bhh[cb];
    bias[g] = b1 + b2;
  }

  // zero h buffers (h(0)=0); all 4 rows fully rewritten each step
  for (int i = tid; i < 2 * 4 * HSTR; i += 512) hbuf[i] = 0;

  // x prefetch: 4 rows x 63 cols = 252 threads; distance-2 pipeline
  const int xrow = tid / DD;
  const int xd   = tid - xrow * DD;
  const bool xthr = (tid < CHUNK * DD);
  const float* xptr = X + ((size_t)(b0 + xrow) * TT) * DD + xd;
  float xv_pend = 0.f;
  if (tid >= CHUNK * DD && tid < 256) {
    // zero x pad columns once (k=63 pad within each row, both slots)
    const int rr = tid & 3;
    xbuf[rr * XSTR + DD] = 0;
    xbuf[4 * XSTR + rr * XSTR + DD] = 0;
  }
  if (xthr) {
    xbuf[xrow * XSTR + xd] = f2bf(xptr[0]);   // slot 0 = x(0)
    xv_pend = xptr[DD];                        // x(1)
    xptr += 2 * DD;
  }
  __syncthreads();

  float cc = 0.f, hv = 0.f;   // ONE element per lane: (batch=br, col=wave*16+quad*4+p)
  const int hcol = wave * 16 + quad * 4 + p;

  for (int t = 0; t < TT; ++t) {
    const int xcur = (t & 1) * (4 * XSTR);
    const int hcur = (t & 1) * (4 * HSTR);

    // issue x(t+2) load early; stays in flight across the lgkm-only barrier
    float xv_new = 0.f;
    const bool pf2 = xthr && (t + 2 < TT);
    if (pf2) { xv_new = *xptr; xptr += DD; }

    // B-fragments: row br (l15&3) -> 4-way same-address broadcast, 2-way banks
    bf16x8 Bh_[4], Bx_[2];
#pragma unroll
    for (int ks = 0; ks < 4; ++ks)
      Bh_[ks] = *(const bf16x8*)&hbuf[hcur + br * HSTR + ks * 32 + quad * 8];
#pragma unroll
    for (int ks = 0; ks < 2; ++ks)
      Bx_[ks] = *(const bf16x8*)&xbuf[xcur + br * XSTR + ks * 32 + quad * 8];

    // ---- MFMA: acc[g] = bias[g] + W_g @ [h;x]^T (4 independent chains) ----
    f32x4 acc[4];
#pragma unroll
    for (int g = 0; g < 4; ++g)
      acc[g] = __builtin_amdgcn_mfma_f32_16x16x32_bf16(Ah[g][0], Bh_[0], bias[g], 0, 0, 0);
#pragma unroll
    for (int ks = 1; ks < 4; ++ks)
#pragma unroll
      for (int g = 0; g < 4; ++g)
        acc[g] = __builtin_amdgcn_mfma_f32_16x16x32_bf16(Ah[g][ks], Bh_[ks], acc[g], 0, 0, 0);
#pragma unroll
    for (int ks = 0; ks < 2; ++ks)
#pragma unroll
      for (int g = 0; g < 4; ++g)
        acc[g] = __builtin_amdgcn_mfma_f32_16x16x32_bf16(Axw[g][ks], Bx_[ks], acc[g], 0, 0, 0);

    // ---- select register p (2 v_cmp + 12 cndmask), elementwise 1 elem/lane ----
    const bool s0 = (l15 & 4) != 0;
    const bool s1 = (l15 & 8) != 0;
    float gv4[4];
#pragma unroll
    for (int g = 0; g < 4; ++g) {
      const float a01 = s0 ? acc[g][1] : acc[g][0];
      const float a23 = s0 ? acc[g][3] : acc[g][2];
      gv4[g] = s1 ? a23 : a01;
    }
    const float iv = sigm(gv4[0]);
    const float fv = sigm(gv4[1]);
    const float gg = tanh_fast(gv4[2]);
    const float ov = sigm(gv4[3]);
    cc = fv * cc + iv * gg;
    hv = ov * tanh_fast(cc);
    hbuf[(hcur ^ (4 * HSTR)) + br * HSTR + hcol] = f2bf(hv);

    if (xthr && (t + 1 < TT))
      xbuf[(xcur ^ (4 * XSTR)) + xrow * XSTR + xd] = f2bf(xv_pend);
    xv_pend = xv_new;
    LDS_BARRIER();   // the ONE barrier: h/x produced -> consumed next step
  }

  // ---- epilogue: forward half of FC (fp32, no bias) ----
  fst[br * HH + hcol] = hv;
  __syncthreads();
  if (tid < CHUNK * 14) {
    const int rr = tid / 14, o = tid - rr * 14;
    const float* wr = Wfc + (size_t)o * (2 * HH);
    float acc = 0.f;
#pragma unroll 16
    for (int k = 0; k < HH; ++k) acc += wr[k] * fst[rr * HH + k];
    out[(size_t)(b0 + rr) * 14 + o] = acc;
  }
}

// Backward direction collapses to ONE cell step on x[:,T-1] (h0=c0=0),
// done in exact fp32, plus the backward half of the FC (+ biases).
__global__ __launch_bounds__(256, 2)
void lstm_bwd_fc_kernel(const float* __restrict__ X,
                        const float* __restrict__ Wih_b,
                        const float* __restrict__ bih_b,
                        const float* __restrict__ bhh_b,
                        const float* __restrict__ Wfc,
                        const float* __restrict__ bfc,
                        float* __restrict__ out) {
  __shared__ float xl[DD];
  __shared__ float glb[4 * HH];
  __shared__ float hl[HH];
  __shared__ float pl[14 * 8];
  const int b = blockIdx.x;
  const int tid = threadIdx.x;

  if (tid < DD) xl[tid] = X[((size_t)b * TT + (TT - 1)) * DD + tid];
  __syncthreads();

#pragma unroll
  for (int u = 0; u < 2; ++u) {
    const int n = tid * 2 + u;
    const float* wr = Wih_b + (size_t)n * DD;
    float acc = bih_b[n] + bhh_b[n];
#pragma unroll
    for (int k = 0; k < DD; ++k) acc += wr[k] * xl[k];
    glb[n] = acc;
  }
  __syncthreads();

  if (tid < HH) {
    float iv = sigm(glb[0 * HH + tid]);
    float gv = tanh_fast(glb[2 * HH + tid]);
    float ov = sigm(glb[3 * HH + tid]);
    hl[tid] = ov * tanh_fast(iv * gv);   // c = f*0 + i*g
  }
  __syncthreads();

  if (tid < 14 * 8) {
    const int o = tid >> 3, kp = tid & 7;
    const float* wr = Wfc + (size_t)o * (2 * HH) + HH;
    float acc = 0.f;
#pragma unroll
    for (int i = 0; i < 16; ++i) {
      const int jj = kp * 16 + i;
      acc += wr[jj] * hl[jj];
    }
    pl[tid] = acc;
  }
  __syncthreads();

  if (tid < 14) {
    float acc = bfc[tid];
#pragma unroll
    for (int i = 0; i < 8; ++i) acc += pl[tid * 8 + i];
    out[(size_t)b * 14 + tid] += acc;   // add to forward partial
  }
}

extern "C" void kernel_launch(void* const* d_in, const int* in_sizes, int n_in,
                              void* d_out, int out_size, void* d_ws, size_t ws_size,
                              hipStream_t stream) {
  const float* X     = (const float*)d_in[0];
  const float* Wih_f = (const float*)d_in[1];
  const float* Whh_f = (const float*)d_in[2];
  const float* bih_f = (const float*)d_in[3];
  const float* bhh_f = (const float*)d_in[4];
  const float* Wih_b = (const float*)d_in[5];
  // d_in[6] = W_hh_b: unused (backward dir needs only one step from zero state)
  const float* bih_b = (const float*)d_in[7];
  const float* bhh_b = (const float*)d_in[8];
  const float* Wfc   = (const float*)d_in[9];
  const float* bfc   = (const float*)d_in[10];
  float* out = (float*)d_out;

  lstm_fwd_kernel<<<BB / CHUNK, 512, 0, stream>>>(X, Wih_f, Whh_f, bih_f, bhh_f, Wfc, out);
  lstm_bwd_fc_kernel<<<BB, 256, 0, stream>>>(X, Wih_b, bih_b, bhh_b, Wfc, bfc, out);
}